// Round 3
// baseline (178.709 us; speedup 1.0000x reference)
//
#include <hip/hip_runtime.h>

#define NDIM 64   // D
#define FDIM 128  // 2D

typedef _Float16 half8 __attribute__((ext_vector_type(8)));

// W1 [64][128] -> W1T [128][64]  (W1T[k][j] = W1[j][k])
__global__ void w1_transpose_kernel(const float* __restrict__ W1,
                                    float* __restrict__ W1T) {
    int i = blockIdx.x * blockDim.x + threadIdx.x;
    if (i < NDIM * FDIM) {
        int j = i >> 7;      // W1 row (output unit)
        int k = i & 127;     // W1 col (input feature)
        W1T[k * NDIM + j] = W1[i];
    }
}

// Per-node half-layer: thread t = (half, node).
//   half==0: Ya[n][j] = b1[j] + sum_k x[n][k] * W1[j][k]       (k = 0..63)
//   half==1: Yb[n][j] =          sum_k x[n][k] * W1[j][64+k]
// Stored as f16 rows of 128 B for the edge-gather kernel.
__global__ __launch_bounds__(256) void node_mlp_kernel(
    const float* __restrict__ x,     // [N][64]
    const float* __restrict__ W1T,   // [128][64]
    const float* __restrict__ b1,    // [64]
    _Float16* __restrict__ Ya,       // [N][64]
    _Float16* __restrict__ Yb,       // [N][64]
    int N, int Npad)
{
    int t = blockIdx.x * blockDim.x + threadIdx.x;
    if (t >= 2 * Npad) return;                    // wave-uniform (Npad%64==0)
    int half = (t >= Npad) ? 1 : 0;               // wave-uniform by construction
    half = __builtin_amdgcn_readfirstlane(half);
    int node = t - half * Npad;
    int nodeL = node < N ? node : N - 1;          // clamp pad-lane loads

    const float4* xr = (const float4*)(x + (size_t)nodeL * NDIM);
    const float* wt = W1T + half * 64 * NDIM;     // k-rows for this half

    float acc[NDIM];
    #pragma unroll
    for (int j = 0; j < NDIM; j++) acc[j] = half ? 0.f : b1[j];

    #pragma unroll 1
    for (int k4 = 0; k4 < 16; k4++) {
        float4 f = xr[k4];
        const float* w = wt + k4 * 4 * NDIM;      // wave-uniform -> s_load
        #pragma unroll
        for (int j = 0; j < NDIM; j++)
            acc[j] += w[j] * f.x + w[NDIM + j] * f.y
                    + w[2 * NDIM + j] * f.z + w[3 * NDIM + j] * f.w;
    }

    if (node < N) {
        _Float16* dst = (half ? Yb : Ya) + (size_t)node * NDIM;
        #pragma unroll
        for (int i = 0; i < 8; i++) {
            half8 o;
            #pragma unroll
            for (int u = 0; u < 8; u++) o[u] = (_Float16)acc[i * 8 + u];
            *(half8*)(dst + i * 8) = o;
        }
    }
}

// Per-edge: out[e] = b2 + sum_j W2[j] * relu(Ya[s][j] + Yb[d][j])
__global__ __launch_bounds__(256) void edge_combine_kernel(
    const _Float16* __restrict__ Ya,
    const _Float16* __restrict__ Yb,
    const int* __restrict__ ei,      // [2E]
    const float* __restrict__ W2,    // [64]
    const float* __restrict__ b2,    // [1]
    float* __restrict__ out,         // [E]
    int E)
{
    int e = blockIdx.x * blockDim.x + threadIdx.x;
    if (e >= E) return;
    int s = ei[e];
    int d = ei[E + e];
    const half8* pa = (const half8*)(Ya + (size_t)s * NDIM);
    const half8* pb = (const half8*)(Yb + (size_t)d * NDIM);

    // 16 independent 16B gathers, fully unrolled -> all in flight
    half8 a[8], b[8];
    #pragma unroll
    for (int i = 0; i < 8; i++) { a[i] = pa[i]; b[i] = pb[i]; }

    float acc = 0.f;
    #pragma unroll
    for (int i = 0; i < 8; i++) {
        #pragma unroll
        for (int u = 0; u < 8; u++) {
            float h = (float)a[i][u] + (float)b[i][u];
            h = h > 0.f ? h : 0.f;
            acc = fmaf(W2[i * 8 + u], h, acc);   // W2 wave-uniform -> s_load
        }
    }
    out[e] = acc + b2[0];
}

// ---------------- fp32 fallback (round-1 kernel) if ws too small --------------
__global__ __launch_bounds__(256) void edge_mlp_fp32_kernel(
    const float* __restrict__ x, const int* __restrict__ ei,
    const float* __restrict__ W1T, const float* __restrict__ b1,
    const float* __restrict__ W2, const float* __restrict__ b2,
    float* __restrict__ out, int E)
{
    int e = blockIdx.x * blockDim.x + threadIdx.x;
    if (e >= E) return;
    int s = ei[e];
    int d = ei[E + e];
    const float4* xs = (const float4*)(x + (size_t)s * NDIM);
    const float4* xd = (const float4*)(x + (size_t)d * NDIM);
    float h[NDIM];
    #pragma unroll
    for (int j = 0; j < NDIM; j++) h[j] = b1[j];
    #pragma unroll 1
    for (int k4 = 0; k4 < 16; k4++) {
        float4 f = xs[k4];
        const float* w = W1T + k4 * 4 * NDIM;
        #pragma unroll
        for (int j = 0; j < NDIM; j++)
            h[j] += w[j] * f.x + w[NDIM + j] * f.y + w[2 * NDIM + j] * f.z + w[3 * NDIM + j] * f.w;
    }
    #pragma unroll 1
    for (int k4 = 0; k4 < 16; k4++) {
        float4 f = xd[k4];
        const float* w = W1T + (16 + k4) * 4 * NDIM;
        #pragma unroll
        for (int j = 0; j < NDIM; j++)
            h[j] += w[j] * f.x + w[NDIM + j] * f.y + w[2 * NDIM + j] * f.z + w[3 * NDIM + j] * f.w;
    }
    float acc = b2[0];
    #pragma unroll
    for (int j = 0; j < NDIM; j++) {
        float hj = h[j] > 0.f ? h[j] : 0.f;
        acc += W2[j] * hj;
    }
    out[e] = acc;
}

extern "C" void kernel_launch(void* const* d_in, const int* in_sizes, int n_in,
                              void* d_out, int out_size, void* d_ws, size_t ws_size,
                              hipStream_t stream) {
    const float* x  = (const float*)d_in[0];
    const int*   ei = (const int*)d_in[1];
    const float* W1 = (const float*)d_in[2];
    const float* b1 = (const float*)d_in[3];
    const float* W2 = (const float*)d_in[4];
    const float* b2 = (const float*)d_in[5];
    float* out = (float*)d_out;
    const int E = out_size;
    const int N = in_sizes[0] / NDIM;
    const int Npad = ((N + 63) / 64) * 64;

    const size_t w1t_bytes = (size_t)NDIM * FDIM * sizeof(float);   // 32 KB
    const size_t tbl_bytes = (size_t)N * NDIM * sizeof(_Float16);   // 12.8 MB
    const size_t need = w1t_bytes + 2 * tbl_bytes;

    float* W1T = (float*)d_ws;
    w1_transpose_kernel<<<(NDIM * FDIM + 255) / 256, 256, 0, stream>>>(W1, W1T);

    if (ws_size >= need) {
        _Float16* Ya = (_Float16*)((char*)d_ws + w1t_bytes);
        _Float16* Yb = Ya + (size_t)N * NDIM;

        int nthreads = 2 * Npad;
        node_mlp_kernel<<<(nthreads + 255) / 256, 256, 0, stream>>>(
            x, W1T, b1, Ya, Yb, N, Npad);

        edge_combine_kernel<<<(E + 255) / 256, 256, 0, stream>>>(
            Ya, Yb, ei, W2, b2, out, E);
    } else {
        edge_mlp_fp32_kernel<<<(E + 255) / 256, 256, 0, stream>>>(
            x, ei, W1T, b1, W2, b2, out, E);
    }
}

// Round 4
// 162.049 us; speedup vs baseline: 1.1028x; 1.1028x over previous
//
#include <hip/hip_runtime.h>

#define NDIM 64   // D
#define FDIM 128  // 2D

typedef _Float16 half8 __attribute__((ext_vector_type(8)));
typedef float    float4v __attribute__((ext_vector_type(4)));

// ---------------------------------------------------------------------------
// Kernel 1: per-node half-layers via MFMA.
//   Yab[n][j]    = b1[j] + sum_k x[n][k] * W1[j][k]        (j = 0..63,  "Ya")
//   Yab[n][64+j] =         sum_k x[n][k] * W1[j][64+k]     (j = 0..63,  "Yb")
// One wave = 16 nodes x 128 cols, K=64 (2 MFMA k-steps). fp32->f16 inline.
// B-fragment for col jj needs 8 consecutive k of Wcomb[k][jj], which is 8
// consecutive elements of W1 row (jj&63) at offset (jj>>6)*64 -- native layout.
// ---------------------------------------------------------------------------
__global__ __launch_bounds__(256) void node_gemm_kernel(
    const float* __restrict__ x,    // [N][64]
    const float* __restrict__ W1,   // [64][128]
    const float* __restrict__ b1,   // [64]
    _Float16* __restrict__ Yab,     // [N][128]
    int N)
{
    const int wave = threadIdx.x >> 6;
    const int lane = threadIdx.x & 63;
    const int c = lane & 15;   // A: node-in-tile | B/C: col-in-tile
    const int g = lane >> 4;   // k-group / C row-group

    const int node0 = (blockIdx.x * 4 + wave) * 16;
    if (node0 >= N) return;    // wave-uniform (N % 16 == 0)

    float4v C[8];
    #pragma unroll
    for (int nt = 0; nt < 8; nt++) C[nt] = (float4v){0.f, 0.f, 0.f, 0.f};

    #pragma unroll
    for (int kk = 0; kk < 2; kk++) {
        // A fragment: row m = node0+c, k = kk*32 + g*8 + j
        const float* ap = x + (size_t)(node0 + c) * NDIM + kk * 32 + g * 8;
        float4v a0 = *(const float4v*)ap;
        float4v a1 = *(const float4v*)(ap + 4);
        half8 A;
        A[0] = (_Float16)a0[0]; A[1] = (_Float16)a0[1];
        A[2] = (_Float16)a0[2]; A[3] = (_Float16)a0[3];
        A[4] = (_Float16)a1[0]; A[5] = (_Float16)a1[1];
        A[6] = (_Float16)a1[2]; A[7] = (_Float16)a1[3];

        #pragma unroll
        for (int nt = 0; nt < 8; nt++) {
            const int jj = nt * 16 + c;
            const float* bp = W1 + (size_t)(jj & 63) * FDIM + (jj >> 6) * 64
                              + kk * 32 + g * 8;
            float4v w0 = *(const float4v*)bp;
            float4v w1 = *(const float4v*)(bp + 4);
            half8 B;
            B[0] = (_Float16)w0[0]; B[1] = (_Float16)w0[1];
            B[2] = (_Float16)w0[2]; B[3] = (_Float16)w0[3];
            B[4] = (_Float16)w1[0]; B[5] = (_Float16)w1[1];
            B[6] = (_Float16)w1[2]; B[7] = (_Float16)w1[3];
            C[nt] = __builtin_amdgcn_mfma_f32_16x16x32_f16(A, B, C[nt], 0, 0, 0);
        }
    }

    // Epilogue: add b1 to the Ya half (cols < 64), store f16.
    // C layout: col = c (within tile nt), row = g*4 + r.
    #pragma unroll
    for (int nt = 0; nt < 8; nt++) {
        const float badd = (nt < 4) ? b1[nt * 16 + c] : 0.f;
        #pragma unroll
        for (int r = 0; r < 4; r++) {
            Yab[(size_t)(node0 + g * 4 + r) * FDIM + nt * 16 + c] =
                (_Float16)(C[nt][r] + badd);
        }
    }
}

// ---------------------------------------------------------------------------
// Kernel 2: per-edge combine.
//   out[e] = b2 + sum_j W2[j] * relu(Yab[s][j] + Yab[d][64+j])
// 16 independent 16 B gathers per thread, fully in flight.
// ---------------------------------------------------------------------------
__global__ __launch_bounds__(256) void edge_combine_kernel(
    const _Float16* __restrict__ Yab,  // [N][128]
    const int* __restrict__ ei,        // [2E]
    const float* __restrict__ W2,      // [64]
    const float* __restrict__ b2,      // [1]
    float* __restrict__ out,           // [E]
    int E)
{
    int e = blockIdx.x * blockDim.x + threadIdx.x;
    if (e >= E) return;
    int s = ei[e];
    int d = ei[E + e];
    const half8* pa = (const half8*)(Yab + (size_t)s * FDIM);        // Ya half
    const half8* pb = (const half8*)(Yab + (size_t)d * FDIM + 64);   // Yb half

    half8 a[8], b[8];
    #pragma unroll
    for (int i = 0; i < 8; i++) { a[i] = pa[i]; b[i] = pb[i]; }

    float acc = 0.f;
    #pragma unroll
    for (int i = 0; i < 8; i++) {
        #pragma unroll
        for (int u = 0; u < 8; u++) {
            float h = (float)a[i][u] + (float)b[i][u];
            h = h > 0.f ? h : 0.f;
            acc = fmaf(W2[i * 8 + u], h, acc);   // W2 wave-uniform -> s_load
        }
    }
    out[e] = acc + b2[0];
}

// ---------------- fp32 fallback (ws too small; not expected) -----------------
__global__ __launch_bounds__(256) void edge_mlp_fp32_kernel(
    const float* __restrict__ x, const int* __restrict__ ei,
    const float* __restrict__ W1, const float* __restrict__ b1,
    const float* __restrict__ W2, const float* __restrict__ b2,
    float* __restrict__ out, int E)
{
    int e = blockIdx.x * blockDim.x + threadIdx.x;
    if (e >= E) return;
    int s = ei[e];
    int d = ei[E + e];
    const float* xs = x + (size_t)s * NDIM;
    const float* xd = x + (size_t)d * NDIM;
    float acc = b2[0];
    for (int j = 0; j < NDIM; j++) {
        float h = b1[j];
        for (int k = 0; k < NDIM; k++) {
            h += xs[k] * W1[j * FDIM + k] + xd[k] * W1[j * FDIM + 64 + k];
        }
        acc += W2[j] * (h > 0.f ? h : 0.f);
    }
    out[e] = acc;
}

extern "C" void kernel_launch(void* const* d_in, const int* in_sizes, int n_in,
                              void* d_out, int out_size, void* d_ws, size_t ws_size,
                              hipStream_t stream) {
    const float* x  = (const float*)d_in[0];
    const int*   ei = (const int*)d_in[1];
    const float* W1 = (const float*)d_in[2];
    const float* b1 = (const float*)d_in[3];
    const float* W2 = (const float*)d_in[4];
    const float* b2 = (const float*)d_in[5];
    float* out = (float*)d_out;
    const int E = out_size;
    const int N = in_sizes[0] / NDIM;

    const size_t tbl_bytes = (size_t)N * FDIM * sizeof(_Float16);  // 25.6 MB

    if (ws_size >= tbl_bytes && (N % 16) == 0) {
        _Float16* Yab = (_Float16*)d_ws;
        const int nblocks = (N + 63) / 64;   // 4 waves x 16 nodes per block
        node_gemm_kernel<<<nblocks, 256, 0, stream>>>(x, W1, b1, Yab, N);
        edge_combine_kernel<<<(E + 255) / 256, 256, 0, stream>>>(
            Yab, ei, W2, b2, out, E);
    } else {
        edge_mlp_fp32_kernel<<<(E + 255) / 256, 256, 0, stream>>>(
            x, ei, W1, b1, W2, b2, out, E);
    }
}

// Round 5
// 143.912 us; speedup vs baseline: 1.2418x; 1.1260x over previous
//
#include <hip/hip_runtime.h>

#define NDIM 64   // D
#define FDIM 128  // 2D

typedef _Float16 half8 __attribute__((ext_vector_type(8)));
typedef float    float4v __attribute__((ext_vector_type(4)));

// ---------------------------------------------------------------------------
// Kernel 1: per-node half-layers via MFMA.  (UNCHANGED from round 4)
//   Yab[n][j]    = b1[j] + sum_k x[n][k] * W1[j][k]        (j = 0..63,  "Ya")
//   Yab[n][64+j] =         sum_k x[n][k] * W1[j][64+k]     (j = 0..63,  "Yb")
// ---------------------------------------------------------------------------
__global__ __launch_bounds__(256) void node_gemm_kernel(
    const float* __restrict__ x,    // [N][64]
    const float* __restrict__ W1,   // [64][128]
    const float* __restrict__ b1,   // [64]
    _Float16* __restrict__ Yab,     // [N][128]
    int N)
{
    const int wave = threadIdx.x >> 6;
    const int lane = threadIdx.x & 63;
    const int c = lane & 15;   // A: node-in-tile | B/C: col-in-tile
    const int g = lane >> 4;   // k-group / C row-group

    const int node0 = (blockIdx.x * 4 + wave) * 16;
    if (node0 >= N) return;    // wave-uniform (N % 16 == 0)

    float4v C[8];
    #pragma unroll
    for (int nt = 0; nt < 8; nt++) C[nt] = (float4v){0.f, 0.f, 0.f, 0.f};

    #pragma unroll
    for (int kk = 0; kk < 2; kk++) {
        const float* ap = x + (size_t)(node0 + c) * NDIM + kk * 32 + g * 8;
        float4v a0 = *(const float4v*)ap;
        float4v a1 = *(const float4v*)(ap + 4);
        half8 A;
        A[0] = (_Float16)a0[0]; A[1] = (_Float16)a0[1];
        A[2] = (_Float16)a0[2]; A[3] = (_Float16)a0[3];
        A[4] = (_Float16)a1[0]; A[5] = (_Float16)a1[1];
        A[6] = (_Float16)a1[2]; A[7] = (_Float16)a1[3];

        #pragma unroll
        for (int nt = 0; nt < 8; nt++) {
            const int jj = nt * 16 + c;
            const float* bp = W1 + (size_t)(jj & 63) * FDIM + (jj >> 6) * 64
                              + kk * 32 + g * 8;
            float4v w0 = *(const float4v*)bp;
            float4v w1 = *(const float4v*)(bp + 4);
            half8 B;
            B[0] = (_Float16)w0[0]; B[1] = (_Float16)w0[1];
            B[2] = (_Float16)w0[2]; B[3] = (_Float16)w0[3];
            B[4] = (_Float16)w1[0]; B[5] = (_Float16)w1[1];
            B[6] = (_Float16)w1[2]; B[7] = (_Float16)w1[3];
            C[nt] = __builtin_amdgcn_mfma_f32_16x16x32_f16(A, B, C[nt], 0, 0, 0);
        }
    }

    #pragma unroll
    for (int nt = 0; nt < 8; nt++) {
        const float badd = (nt < 4) ? b1[nt * 16 + c] : 0.f;
        #pragma unroll
        for (int r = 0; r < 4; r++) {
            Yab[(size_t)(node0 + g * 4 + r) * FDIM + nt * 16 + c] =
                (_Float16)(C[nt][r] + badd);
        }
    }
}

// ---------------------------------------------------------------------------
// Kernel 2: per-edge combine, GROUP-COOPERATIVE gather (new in round 5).
// Wave = 8 groups x 8 lanes. Step t: group grp handles edge e0 + t*8 + grp;
// its 8 lanes load the 128B Ya[s] / Yb[d] rows cooperatively (16 B each,
// contiguous within the group -> ~16 cache lines per load inst instead of 64).
// Partial dot over 8 j's per lane, shfl_xor-reduce over the group, lane
// j8==t keeps the result; final store is one fully-coalesced 256 B per wave.
//   out[e] = b2 + sum_j W2[j] * relu(Yab[s][j] + Yab[d][64+j])
// ---------------------------------------------------------------------------
__global__ __launch_bounds__(256) void edge_combine_kernel(
    const _Float16* __restrict__ Yab,  // [N][128]
    const int* __restrict__ ei,        // [2E]
    const float* __restrict__ W2,      // [64]
    const float* __restrict__ b2,      // [1]
    float* __restrict__ out,           // [E]
    int E)
{
    const int lane = threadIdx.x & 63;
    const int wave = threadIdx.x >> 6;
    const int grp  = lane >> 3;   // 0..7: which edge of the step
    const int j8   = lane & 7;    // 0..7: which 8-wide j-chunk of the row

    const long e0 = (long)blockIdx.x * 256 + wave * 64;
    if (e0 >= E) return;          // wave-uniform (E % 64 == 0)

    // Per-lane W2 slice (32 B, aligned; broadcast across the 8 groups via L1)
    float4v w2lo = *(const float4v*)(W2 + j8 * 8);
    float4v w2hi = *(const float4v*)(W2 + j8 * 8 + 4);
    const float b2v = b2[0];

    float keep = 0.f;
    #pragma unroll
    for (int t = 0; t < 8; t++) {
        const long e = e0 + t * 8 + grp;
        const int s = ei[e];
        const int d = ei[E + e];
        half8 a = *(const half8*)(Yab + (size_t)s * FDIM + j8 * 8);
        half8 b = *(const half8*)(Yab + (size_t)d * FDIM + 64 + j8 * 8);

        float acc = 0.f;
        #pragma unroll
        for (int u = 0; u < 8; u++) {
            float h = (float)a[u] + (float)b[u];
            h = h > 0.f ? h : 0.f;
            acc = fmaf(u < 4 ? w2lo[u] : w2hi[u - 4], h, acc);
        }
        acc += __shfl_xor(acc, 1, 64);
        acc += __shfl_xor(acc, 2, 64);
        acc += __shfl_xor(acc, 4, 64);
        if (j8 == t) keep = acc;
    }
    // lane (grp, j8) holds edge e0 + j8*8 + grp -> 64 lanes cover [e0, e0+64)
    out[e0 + j8 * 8 + grp] = keep + b2v;
}

// ---------------- fp32 fallback (ws too small; not expected) -----------------
__global__ __launch_bounds__(256) void edge_mlp_fp32_kernel(
    const float* __restrict__ x, const int* __restrict__ ei,
    const float* __restrict__ W1, const float* __restrict__ b1,
    const float* __restrict__ W2, const float* __restrict__ b2,
    float* __restrict__ out, int E)
{
    int e = blockIdx.x * blockDim.x + threadIdx.x;
    if (e >= E) return;
    int s = ei[e];
    int d = ei[E + e];
    const float* xs = x + (size_t)s * NDIM;
    const float* xd = x + (size_t)d * NDIM;
    float acc = b2[0];
    for (int j = 0; j < NDIM; j++) {
        float h = b1[j];
        for (int k = 0; k < NDIM; k++) {
            h += xs[k] * W1[j * FDIM + k] + xd[k] * W1[j * FDIM + 64 + k];
        }
        acc += W2[j] * (h > 0.f ? h : 0.f);
    }
    out[e] = acc;
}

extern "C" void kernel_launch(void* const* d_in, const int* in_sizes, int n_in,
                              void* d_out, int out_size, void* d_ws, size_t ws_size,
                              hipStream_t stream) {
    const float* x  = (const float*)d_in[0];
    const int*   ei = (const int*)d_in[1];
    const float* W1 = (const float*)d_in[2];
    const float* b1 = (const float*)d_in[3];
    const float* W2 = (const float*)d_in[4];
    const float* b2 = (const float*)d_in[5];
    float* out = (float*)d_out;
    const int E = out_size;
    const int N = in_sizes[0] / NDIM;

    const size_t tbl_bytes = (size_t)N * FDIM * sizeof(_Float16);  // 25.6 MB

    if (ws_size >= tbl_bytes && (N % 16) == 0 && (E % 64) == 0) {
        _Float16* Yab = (_Float16*)d_ws;
        const int nblocks = (N + 63) / 64;   // 4 waves x 16 nodes per block
        node_gemm_kernel<<<nblocks, 256, 0, stream>>>(x, W1, b1, Yab, N);
        edge_combine_kernel<<<(E + 255) / 256, 256, 0, stream>>>(
            Yab, ei, W2, b2, out, E);
    } else {
        edge_mlp_fp32_kernel<<<(E + 255) / 256, 256, 0, stream>>>(
            x, ei, W1, b1, W2, b2, out, E);
    }
}

// Round 6
// 133.252 us; speedup vs baseline: 1.3411x; 1.0800x over previous
//
#include <hip/hip_runtime.h>

#define NDIM 64   // D
#define FDIM 128  // 2D

typedef _Float16 half8  __attribute__((ext_vector_type(8)));
typedef _Float16 half4v __attribute__((ext_vector_type(4)));
typedef float    float4v __attribute__((ext_vector_type(4)));

// ---------------------------------------------------------------------------
// Prep: Wcomb[j][k] (f16, [128][64]) = j<64 ? W1[j][k] : W1[j-64][64+k]
// A-operand layout for the node GEMM: row j, 8 consecutive k per lane -> 16B.
// ---------------------------------------------------------------------------
__global__ __launch_bounds__(256) void prep_wcomb_kernel(
    const float* __restrict__ W1, _Float16* __restrict__ Wcomb)
{
    int i = blockIdx.x * blockDim.x + threadIdx.x;   // 8192 = 128*64
    if (i >= FDIM * NDIM) return;
    int j = i >> 6;
    int k = i & 63;
    float v = (j < NDIM) ? W1[j * FDIM + k] : W1[(j - NDIM) * FDIM + NDIM + k];
    Wcomb[i] = (_Float16)v;
}

// ---------------------------------------------------------------------------
// Kernel 1 (v2): node half-layers via MFMA, operands SWAPPED vs round 5.
//   A = Wcomb tile  (m = j,    8k per lane, straight 16B f16 loads, L1-hot)
//   B = x^T tile    (n = node, 8k per lane, 16B f32x2 loads + inline cvt)
//   C lane(c,g) reg r = Yab_pre[node0+c][ j = mt*16 + g*4 + r ]
// -> per lane, 4 consecutive j per mt: 8-byte stores (8 per lane vs 32x2B).
//   Yab[n][j]    = b1[j] + sum_k x[n][k] * W1[j][k]        (j < 64)
//   Yab[n][64+j] =         sum_k x[n][k] * W1[j][64+k]
// ---------------------------------------------------------------------------
__global__ __launch_bounds__(256) void node_gemm_kernel(
    const float* __restrict__ x,        // [N][64]
    const _Float16* __restrict__ Wcomb, // [128][64]
    const float* __restrict__ b1,       // [64]
    _Float16* __restrict__ Yab,         // [N][128]
    int N)
{
    const int wave = threadIdx.x >> 6;
    const int lane = threadIdx.x & 63;
    const int c = lane & 15;   // A: j-in-tile | B/C: node-in-tile
    const int g = lane >> 4;   // k-group / C row-group

    const int node0 = (blockIdx.x * 4 + wave) * 16;
    if (node0 >= N) return;    // wave-uniform (N % 16 == 0)

    // B fragments: x[node0+c][kk*32 + g*8 .. +8], f32 -> f16
    half8 Bf[2];
    #pragma unroll
    for (int kk = 0; kk < 2; kk++) {
        const float* bp = x + (size_t)(node0 + c) * NDIM + kk * 32 + g * 8;
        float4v b0 = *(const float4v*)bp;
        float4v b1v_ = *(const float4v*)(bp + 4);
        half8 B;
        B[0] = (_Float16)b0[0]; B[1] = (_Float16)b0[1];
        B[2] = (_Float16)b0[2]; B[3] = (_Float16)b0[3];
        B[4] = (_Float16)b1v_[0]; B[5] = (_Float16)b1v_[1];
        B[6] = (_Float16)b1v_[2]; B[7] = (_Float16)b1v_[3];
        Bf[kk] = B;
    }

    float4v C[8];
    #pragma unroll
    for (int mt = 0; mt < 8; mt++) C[mt] = (float4v){0.f, 0.f, 0.f, 0.f};

    #pragma unroll
    for (int kk = 0; kk < 2; kk++) {
        #pragma unroll
        for (int mt = 0; mt < 8; mt++) {
            half8 Af = *(const half8*)(Wcomb + (size_t)(mt * 16 + c) * NDIM
                                       + kk * 32 + g * 8);
            C[mt] = __builtin_amdgcn_mfma_f32_16x16x32_f16(Af, Bf[kk], C[mt], 0, 0, 0);
        }
    }

    // Epilogue: j = mt*16 + g*4 + r; +b1 for j<64 (mt<4); 8B store per mt.
    #pragma unroll
    for (int mt = 0; mt < 8; mt++) {
        float4v badd = (float4v){0.f, 0.f, 0.f, 0.f};
        if (mt < 4) badd = *(const float4v*)(b1 + mt * 16 + g * 4);
        half4v o;
        #pragma unroll
        for (int r = 0; r < 4; r++) o[r] = (_Float16)(C[mt][r] + badd[r]);
        *(half4v*)(Yab + (size_t)(node0 + c) * FDIM + mt * 16 + g * 4) = o;
    }
}

// ---------------------------------------------------------------------------
// Kernel 2: per-edge combine, group-cooperative gather. (UNCHANGED from R5)
//   out[e] = b2 + sum_j W2[j] * relu(Yab[s][j] + Yab[d][64+j])
// ---------------------------------------------------------------------------
__global__ __launch_bounds__(256) void edge_combine_kernel(
    const _Float16* __restrict__ Yab,  // [N][128]
    const int* __restrict__ ei,        // [2E]
    const float* __restrict__ W2,      // [64]
    const float* __restrict__ b2,      // [1]
    float* __restrict__ out,           // [E]
    int E)
{
    const int lane = threadIdx.x & 63;
    const int wave = threadIdx.x >> 6;
    const int grp  = lane >> 3;   // 0..7: which edge of the step
    const int j8   = lane & 7;    // 0..7: which 8-wide j-chunk of the row

    const long e0 = (long)blockIdx.x * 256 + wave * 64;
    if (e0 >= E) return;          // wave-uniform (E % 64 == 0)

    float4v w2lo = *(const float4v*)(W2 + j8 * 8);
    float4v w2hi = *(const float4v*)(W2 + j8 * 8 + 4);
    const float b2v = b2[0];

    float keep = 0.f;
    #pragma unroll
    for (int t = 0; t < 8; t++) {
        const long e = e0 + t * 8 + grp;
        const int s = ei[e];
        const int d = ei[E + e];
        half8 a = *(const half8*)(Yab + (size_t)s * FDIM + j8 * 8);
        half8 b = *(const half8*)(Yab + (size_t)d * FDIM + 64 + j8 * 8);

        float acc = 0.f;
        #pragma unroll
        for (int u = 0; u < 8; u++) {
            float h = (float)a[u] + (float)b[u];
            h = h > 0.f ? h : 0.f;
            acc = fmaf(u < 4 ? w2lo[u] : w2hi[u - 4], h, acc);
        }
        acc += __shfl_xor(acc, 1, 64);
        acc += __shfl_xor(acc, 2, 64);
        acc += __shfl_xor(acc, 4, 64);
        if (j8 == t) keep = acc;
    }
    out[e0 + j8 * 8 + grp] = keep + b2v;
}

// ---------------- fp32 fallback (ws too small; not expected) -----------------
__global__ __launch_bounds__(256) void edge_mlp_fp32_kernel(
    const float* __restrict__ x, const int* __restrict__ ei,
    const float* __restrict__ W1, const float* __restrict__ b1,
    const float* __restrict__ W2, const float* __restrict__ b2,
    float* __restrict__ out, int E)
{
    int e = blockIdx.x * blockDim.x + threadIdx.x;
    if (e >= E) return;
    int s = ei[e];
    int d = ei[E + e];
    const float* xs = x + (size_t)s * NDIM;
    const float* xd = x + (size_t)d * NDIM;
    float acc = b2[0];
    for (int j = 0; j < NDIM; j++) {
        float h = b1[j];
        for (int k = 0; k < NDIM; k++) {
            h += xs[k] * W1[j * FDIM + k] + xd[k] * W1[j * FDIM + 64 + k];
        }
        acc += W2[j] * (h > 0.f ? h : 0.f);
    }
    out[e] = acc;
}

extern "C" void kernel_launch(void* const* d_in, const int* in_sizes, int n_in,
                              void* d_out, int out_size, void* d_ws, size_t ws_size,
                              hipStream_t stream) {
    const float* x  = (const float*)d_in[0];
    const int*   ei = (const int*)d_in[1];
    const float* W1 = (const float*)d_in[2];
    const float* b1 = (const float*)d_in[3];
    const float* W2 = (const float*)d_in[4];
    const float* b2 = (const float*)d_in[5];
    float* out = (float*)d_out;
    const int E = out_size;
    const int N = in_sizes[0] / NDIM;

    const size_t wcomb_bytes = (size_t)FDIM * NDIM * sizeof(_Float16);  // 16 KB
    const size_t tbl_bytes   = (size_t)N * FDIM * sizeof(_Float16);     // 25.6 MB

    if (ws_size >= wcomb_bytes + tbl_bytes && (N % 16) == 0 && (E % 64) == 0) {
        _Float16* Wcomb = (_Float16*)d_ws;
        _Float16* Yab   = (_Float16*)((char*)d_ws + wcomb_bytes);

        prep_wcomb_kernel<<<(FDIM * NDIM + 255) / 256, 256, 0, stream>>>(W1, Wcomb);

        const int nblocks = (N + 63) / 64;   // 4 waves x 16 nodes per block
        node_gemm_kernel<<<nblocks, 256, 0, stream>>>(x, Wcomb, b1, Yab, N);

        edge_combine_kernel<<<(E + 255) / 256, 256, 0, stream>>>(
            Yab, ei, W2, b2, out, E);
    } else {
        edge_mlp_fp32_kernel<<<(E + 255) / 256, 256, 0, stream>>>(
            x, ei, W1, b1, W2, b2, out, E);
    }
}